// Round 6
// baseline (72.222 us; speedup 1.0000x reference)
//
#include <hip/hip_runtime.h>
#include <hip/hip_bf16.h>

// Problem: B=4096, D_IN=D_H=K=1024.
//   x = input_ @ fq(Wi,4).T + bi ; h = hidden @ fq(Wr,4).T + br
//   out = tanh(LN(x) + LN(h))
// ws layout:
//   +0      : bmax f32[512] (per-block weight absmax; 0..255 Wi, 256..511 Wr)
//   +2048   : scales f32[2] (si, sr) written by quant_k
//   +4096   : Qi  bf16 ints, 2 MB
//   +2M+4096: Qr  bf16 ints, 2 MB
//   +4M+4096: Abf bf16, 8 MB
//   +12M+..: Hbf bf16, 8 MB
//   +20M+..: Xq  bf16 (x pre-LN, unscaled), 8 MB
//   +28M+..: Hq  bf16 (h pre-LN, unscaled), 8 MB

typedef float  f32x4  __attribute__((ext_vector_type(4)));
typedef __bf16 bf16x8 __attribute__((ext_vector_type(8)));
typedef __bf16 bf16x4 __attribute__((ext_vector_type(4)));

#define KDIM 1024

// ---------------- fused: weight absmax (blocks 0..511) + activation cvt (512..2559) ----------------
__global__ __launch_bounds__(256)
void prep1_k(const float* __restrict__ A, const float* __restrict__ Hh,
             const float* __restrict__ Wi, const float* __restrict__ Wr,
             float* __restrict__ bmax,
             __bf16* __restrict__ Abf, __bf16* __restrict__ Hbf)
{
    const int b = blockIdx.x, t = threadIdx.x;
    if (b < 512) {
        const int tensor = b >> 8;
        const float* W = tensor ? Wr : Wi;
        const int lane = t & 63, wid = t >> 6;
        const f32x4* p = (const f32x4*)W;
        const size_t base = (size_t)(b & 255) * 1024;
        float m = 0.f;
#pragma unroll
        for (int k = 0; k < 4; ++k) {
            f32x4 v = p[base + k * 256 + t];
            m = fmaxf(m, fmaxf(fmaxf(fabsf(v[0]), fabsf(v[1])),
                               fmaxf(fabsf(v[2]), fabsf(v[3]))));
        }
#pragma unroll
        for (int o = 32; o >= 1; o >>= 1) m = fmaxf(m, __shfl_xor(m, o));
        __shared__ float wm_[4];
        if (lane == 0) wm_[wid] = m;
        __syncthreads();
        if (t == 0) bmax[b] = fmaxf(fmaxf(wm_[0], wm_[1]), fmaxf(wm_[2], wm_[3]));
        return;
    }
    // activation f32 -> bf16
    const int c = b - 512;                       // 0..2047
    const float* src = (c < 1024) ? A : Hh;
    __bf16* dst = (c < 1024) ? Abf : Hbf;
    const int base = (c & 1023) * 4096;
#pragma unroll
    for (int j = 0; j < 2; ++j) {
        const int e = base + (j * 256 + t) * 8;
        f32x4 v0 = ((const f32x4*)(src + e))[0];
        f32x4 v1 = ((const f32x4*)(src + e))[1];
        bf16x8 o;
#pragma unroll
        for (int i = 0; i < 4; ++i) {
            o[i]     = (__bf16)v0[i];
            o[i + 4] = (__bf16)v1[i];
        }
        *(bf16x8*)(dst + e) = o;
    }
}

// ---------------- quantize weights to integer bf16 (reduces bmax per block) ----------------
__global__ __launch_bounds__(256)
void quant_k(const float* __restrict__ Wi, const float* __restrict__ Wr,
             const float* __restrict__ bmax, float* __restrict__ scales,
             __bf16* __restrict__ Qi, __bf16* __restrict__ Qr)
{
    const int tensor = blockIdx.x >> 8;
    const int b = blockIdx.x & 255;
    const int t = threadIdx.x;
    const int lane = t & 63, wid = t >> 6;

    float m = bmax[tensor * 256 + t];
#pragma unroll
    for (int o = 32; o >= 1; o >>= 1) m = fmaxf(m, __shfl_xor(m, o));
    __shared__ float wm_[4];
    if (lane == 0) wm_[wid] = m;
    __syncthreads();
    m = fmaxf(fmaxf(wm_[0], wm_[1]), fmaxf(wm_[2], wm_[3]));
    const float s = m / 7.0f;
    if (t == 0 && b == 0) scales[tensor] = s;

    const float* W = tensor ? Wr : Wi;
    __bf16* Q = tensor ? Qr : Qi;
#pragma unroll
    for (int j = 0; j < 2; ++j) {
        const int e = b * 4096 + (j * 256 + t) * 8;
        f32x4 v0 = ((const f32x4*)(W + e))[0];
        f32x4 v1 = ((const f32x4*)(W + e))[1];
        bf16x8 o;
#pragma unroll
        for (int i = 0; i < 4; ++i) {
            o[i]     = (__bf16)rintf(v0[i] / s);
            o[i + 4] = (__bf16)rintf(v1[i] / s);
        }
        *(bf16x8*)(Q + e) = o;
    }
}

// ---------------- dual bf16 MFMA GEMM: 256x128 tile, 8-wave ----------------
// A staged via global_load_lds (3 bufs x 32 KB, distance-2 prefetch, one
// barrier per K-step). B operand BYPASSES LDS: each fragment is a contiguous
// 16B of the (L2-resident) quantized weight matrix, loaded global->reg and
// prefetched one K-step ahead (ping-pong regs, fully unrolled => static idx).
//   B frag (kk,ni): row = wn*64+ni*16+l15, elem k = kt*64 + (kk*4+lq)*8
//   (identical bytes to the old swizzled-LDS path: g' = kq^l7 => g = kq).
// vmcnt bookkeeping (issue order per kt: bfv(kt+1):8, DMA A(kt+2):4):
//   steady kt<14: after MFMA wait vmcnt(12)  -> A(kt+1) certified
//   kt==14:       wait vmcnt(8)              -> A(15) certified
// Reads of buf[cur] retire via lgkmcnt(0) before the barrier, so the
// DMA overwrite of buf[(kt+2)%3] at kt+? is race-free (same as round 5).
__global__ __launch_bounds__(512, 2)
void gemm_dual(const __bf16* __restrict__ A0, const __bf16* __restrict__ A1,
               const __bf16* __restrict__ W0, const __bf16* __restrict__ W1,
               __bf16* __restrict__ C0, __bf16* __restrict__ C1)
{
    __shared__ bf16x8 lds[3][2048];   // A tiles only, 96 KB

    // XCD-aware bijective swizzle (256 blocks, 8 XCDs)
    const int b = blockIdx.x;
    const int swz = (b & 7) * 32 + (b >> 3);
    const int which = swz >> 7;
    const int r = swz & 127;
    const int bm = r >> 3, bn = r & 7;     // bm 0..15 (M/256), bn 0..7 (N/128)

    const __bf16* A = which ? A1 : A0;
    const __bf16* W = which ? W1 : W0;
    __bf16*       C = which ? C1 : C0;

    const int t = threadIdx.x;
    const int l = t & 63, w = t >> 6;
    const int wm = w >> 1, wn = w & 1;      // wave grid 4M x 2N, per-wave 64x64
    const int l15 = l & 15, l7 = l & 7, lq = l >> 4;

    const __bf16* gA = A + (size_t)(bm * 256) * KDIM;
    const __bf16* gB = W + (size_t)(bn * 128) * KDIM;

    // A staging source offsets (element units), pre-swizzled for the DMA
    int srcA[4];
#pragma unroll
    for (int j = 0; j < 4; ++j) {
        const int c = j * 512 + t;          // A chunk 0..2047
        const int row = c >> 3, g = (c & 7) ^ (row & 7);
        srcA[j] = row * KDIM + g * 8;
    }

    // B fragment base pointers: 4 rows, kk/kt folded into immediate offsets
    const __bf16* bptr[4];
#pragma unroll
    for (int ni = 0; ni < 4; ++ni)
        bptr[ni] = gB + (size_t)(wn * 64 + ni * 16 + l15) * KDIM + lq * 8;

#define STAGE(bb, kt)                                                          \
    do {                                                                       \
        _Pragma("unroll")                                                      \
        for (int j = 0; j < 4; ++j)                                            \
            __builtin_amdgcn_global_load_lds(                                  \
                (const __attribute__((address_space(1))) unsigned*)(gA + srcA[j] + (kt) * 64), \
                (__attribute__((address_space(3))) unsigned*)(&lds[bb][(j) * 512 + t]), \
                16, 0, 0);                                                     \
    } while (0)

    const f32x4 zero4 = {0.f, 0.f, 0.f, 0.f};
    f32x4 acc[4][4];
#pragma unroll
    for (int mi = 0; mi < 4; ++mi)
#pragma unroll
        for (int ni = 0; ni < 4; ++ni) acc[mi][ni] = zero4;

    bf16x8 bfr[2][2][4];    // [kt&1][kk][ni], all indices static (full unroll)

    // prologue: issue order [A(0):4][B(0):8][A(1):4]
    STAGE(0, 0);
#pragma unroll
    for (int kk = 0; kk < 2; ++kk)
#pragma unroll
        for (int ni = 0; ni < 4; ++ni)
            bfr[0][kk][ni] = *(const bf16x8*)(bptr[ni] + kk * 32);
    STAGE(1, 1);
    asm volatile("s_waitcnt vmcnt(12)" ::: "memory");   // A(0) landed
    __builtin_amdgcn_s_barrier();

#pragma unroll
    for (int kt = 0; kt < 16; ++kt) {
        const bf16x8* LA = &lds[kt % 3][0];
        bf16x8 af[2][4];
#pragma unroll
        for (int kk = 0; kk < 2; ++kk) {
            const int kq = kk * 4 + lq;
#pragma unroll
            for (int mi = 0; mi < 4; ++mi)
                af[kk][mi] = LA[(wm * 64 + mi * 16 + l15) * 8 + (kq ^ l7)];
        }

        if (kt < 15) {      // prefetch B(kt+1) into the other reg bank
#pragma unroll
            for (int kk = 0; kk < 2; ++kk)
#pragma unroll
                for (int ni = 0; ni < 4; ++ni)
                    bfr[(kt + 1) & 1][kk][ni] =
                        *(const bf16x8*)(bptr[ni] + (kt + 1) * 64 + kk * 32);
        }
        if (kt < 14) STAGE((kt + 2) % 3, kt + 2);   // prefetch A(kt+2)

        asm volatile("s_waitcnt lgkmcnt(0)" ::: "memory");   // af ready
        __builtin_amdgcn_sched_barrier(0);

        __builtin_amdgcn_s_setprio(1);
#pragma unroll
        for (int kk = 0; kk < 2; ++kk)
#pragma unroll
            for (int mi = 0; mi < 4; ++mi)
#pragma unroll
                for (int ni = 0; ni < 4; ++ni)
                    acc[mi][ni] = __builtin_amdgcn_mfma_f32_16x16x32_bf16(
                        bfr[kt & 1][kk][ni], af[kk][mi], acc[mi][ni], 0, 0, 0);
        __builtin_amdgcn_s_setprio(0);

        if (kt < 14)       { asm volatile("s_waitcnt vmcnt(12)" ::: "memory"); }
        else if (kt == 14) { asm volatile("s_waitcnt vmcnt(8)"  ::: "memory"); }
        if (kt < 15) __builtin_amdgcn_s_barrier();
    }

    // C write (swapped-operand layout): batch = lane&15 (+mi*16),
    // feat = (lane>>4)*4 + rr (+ni*16); one 8B bf16x4 store per fragment
    const int batch0 = bm * 256 + wm * 64 + l15;
    const int feat0  = bn * 128 + wn * 64 + (lq << 2);
#pragma unroll
    for (int mi = 0; mi < 4; ++mi)
#pragma unroll
        for (int ni = 0; ni < 4; ++ni) {
            bf16x4 o;
#pragma unroll
            for (int rr = 0; rr < 4; ++rr) o[rr] = (__bf16)acc[mi][ni][rr];
            *(bf16x4*)(C + (size_t)(batch0 + mi * 16) * KDIM + feat0 + ni * 16) = o;
        }
#undef STAGE
}

// ---------------- fused scale+bias, LN(x), LN(h), tanh — one row per WAVE ----------------
__global__ __launch_bounds__(256)
void ln_tanh_k(const __bf16* __restrict__ X, const __bf16* __restrict__ Hh,
               const float* __restrict__ bi, const float* __restrict__ br,
               const float* __restrict__ scales, float* __restrict__ out)
{
    const int t = threadIdx.x;
    const int lane = t & 63, wid = t >> 6;
    const int row = blockIdx.x * 4 + wid;
    const float si = scales[0];
    const float sr = scales[1];

    const bf16x8* xp = (const bf16x8*)(X  + (size_t)row * 1024 + lane * 16);
    const bf16x8* hp = (const bf16x8*)(Hh + (size_t)row * 1024 + lane * 16);
    bf16x8 xv0 = xp[0], xv1 = xp[1];
    bf16x8 hv0 = hp[0], hv1 = hp[1];

    float xs[16], hs[16];
    float sx = 0.f, sh = 0.f;
#pragma unroll
    for (int q = 0; q < 4; ++q) {
        f32x4 bviq = ((const f32x4*)bi)[lane * 4 + q];
        f32x4 bvrq = ((const f32x4*)br)[lane * 4 + q];
#pragma unroll
        for (int j = 0; j < 4; ++j) {
            const int e = q * 4 + j;
            const float xf = (e < 8) ? (float)xv0[e] : (float)xv1[e - 8];
            const float hf = (e < 8) ? (float)hv0[e] : (float)hv1[e - 8];
            xs[e] = xf * si + bviq[j];
            hs[e] = hf * sr + bvrq[j];
            sx += xs[e]; sh += hs[e];
        }
    }

#pragma unroll
    for (int o = 32; o >= 1; o >>= 1) { sx += __shfl_xor(sx, o); sh += __shfl_xor(sh, o); }
    const float mx = sx * (1.0f / 1024.0f), mh = sh * (1.0f / 1024.0f);

    float vx = 0.f, vh = 0.f;
#pragma unroll
    for (int e = 0; e < 16; ++e) {
        xs[e] -= mx; hs[e] -= mh;
        vx += xs[e] * xs[e]; vh += hs[e] * hs[e];
    }
#pragma unroll
    for (int o = 32; o >= 1; o >>= 1) { vx += __shfl_xor(vx, o); vh += __shfl_xor(vh, o); }
    const float rsx = rsqrtf(vx * (1.0f / 1024.0f) + 1e-5f);
    const float rsh = rsqrtf(vh * (1.0f / 1024.0f) + 1e-5f);

    float* op = out + (size_t)row * 1024 + lane * 16;
#pragma unroll
    for (int q = 0; q < 4; ++q) {
        f32x4 o4;
#pragma unroll
        for (int j = 0; j < 4; ++j) {
            const int e = q * 4 + j;
            o4[j] = tanhf(xs[e] * rsx + hs[e] * rsh);
        }
        ((f32x4*)op)[q] = o4;
    }
}

extern "C" void kernel_launch(void* const* d_in, const int* in_sizes, int n_in,
                              void* d_out, int out_size, void* d_ws, size_t ws_size,
                              hipStream_t stream)
{
    const float* input_ = (const float*)d_in[0];
    const float* hidden = (const float*)d_in[1];
    const float* Wi     = (const float*)d_in[2];
    const float* bi     = (const float*)d_in[3];
    const float* Wr     = (const float*)d_in[4];
    const float* br     = (const float*)d_in[5];
    float* out = (float*)d_out;

    char* ws = (char*)d_ws;
    float* bmax   = (float*)ws;
    float* scales = (float*)(ws + 2048);
    __bf16* Qi  = (__bf16*)(ws + 4096);
    __bf16* Qr  = (__bf16*)(ws + 4096 + (1u << 21));
    __bf16* Abf = (__bf16*)(ws + 4096 + (2u << 21));
    __bf16* Hbf = (__bf16*)(ws + 4096 + (2u << 21) + (1u << 23));
    __bf16* Xq  = (__bf16*)(ws + 4096 + (2u << 21) + (2u << 23));
    __bf16* Hq  = (__bf16*)(ws + 4096 + (2u << 21) + (3u << 23));

    prep1_k<<<2560, 256, 0, stream>>>(input_, hidden, Wi, Wr, bmax, Abf, Hbf);
    quant_k<<<512, 256, 0, stream>>>(Wi, Wr, bmax, scales, Qi, Qr);
    gemm_dual<<<256, 512, 0, stream>>>(Abf, Hbf, Qi, Qr, Xq, Hq);
    ln_tanh_k<<<1024, 256, 0, stream>>>(Xq, Hq, bi, br, scales, out);
}

// Round 7
// 51.302 us; speedup vs baseline: 1.4078x; 1.4078x over previous
//
#include <hip/hip_runtime.h>
#include <hip/hip_bf16.h>

// Problem: B=4096, D_IN=D_H=K=1024.
//   x = input_ @ fq(Wi,4).T + bi ; h = hidden @ fq(Wr,4).T + br
//   out = tanh(LN(x) + LN(h))
// ws layout:
//   +0      : bmax f32[512] (per-block weight absmax; 0..255 Wi, 256..511 Wr)
//   +2048   : scales f32[2] (si, sr) written by quant_k
//   +4096   : Qi  bf16 ints, 2 MB
//   +2M+4096: Qr  bf16 ints, 2 MB
//   +4M+4096: Xq  bf16 (x pre-LN, unscaled), 8 MB
//   +12M+..: Hq  bf16 (h pre-LN, unscaled), 8 MB

typedef float  f32x4  __attribute__((ext_vector_type(4)));
typedef __bf16 bf16x8 __attribute__((ext_vector_type(8)));
typedef __bf16 bf16x4 __attribute__((ext_vector_type(4)));

#define KDIM 1024

// ---------------- weight absmax (per-block partial max) ----------------
__global__ __launch_bounds__(256)
void absmax_k(const float* __restrict__ Wi, const float* __restrict__ Wr,
              float* __restrict__ bmax)
{
    const int b = blockIdx.x, t = threadIdx.x;
    const int tensor = b >> 8;
    const float* W = tensor ? Wr : Wi;
    const int lane = t & 63, wid = t >> 6;
    const f32x4* p = (const f32x4*)W;
    const size_t base = (size_t)(b & 255) * 1024;
    float m = 0.f;
#pragma unroll
    for (int k = 0; k < 4; ++k) {
        f32x4 v = p[base + k * 256 + t];
        m = fmaxf(m, fmaxf(fmaxf(fabsf(v[0]), fabsf(v[1])),
                           fmaxf(fabsf(v[2]), fabsf(v[3]))));
    }
#pragma unroll
    for (int o = 32; o >= 1; o >>= 1) m = fmaxf(m, __shfl_xor(m, o));
    __shared__ float wm_[4];
    if (lane == 0) wm_[wid] = m;
    __syncthreads();
    if (t == 0) bmax[b] = fmaxf(fmaxf(wm_[0], wm_[1]), fmaxf(wm_[2], wm_[3]));
}

// ---------------- quantize weights to integer bf16 (reduces bmax per block) ----------------
__global__ __launch_bounds__(256)
void quant_k(const float* __restrict__ Wi, const float* __restrict__ Wr,
             const float* __restrict__ bmax, float* __restrict__ scales,
             __bf16* __restrict__ Qi, __bf16* __restrict__ Qr)
{
    const int tensor = blockIdx.x >> 8;
    const int b = blockIdx.x & 255;
    const int t = threadIdx.x;
    const int lane = t & 63, wid = t >> 6;

    float m = bmax[tensor * 256 + t];
#pragma unroll
    for (int o = 32; o >= 1; o >>= 1) m = fmaxf(m, __shfl_xor(m, o));
    __shared__ float wm_[4];
    if (lane == 0) wm_[wid] = m;
    __syncthreads();
    m = fmaxf(fmaxf(wm_[0], wm_[1]), fmaxf(wm_[2], wm_[3]));
    const float s = m / 7.0f;
    if (t == 0 && b == 0) scales[tensor] = s;

    const float* W = tensor ? Wr : Wi;
    __bf16* Q = tensor ? Qr : Qi;
#pragma unroll
    for (int j = 0; j < 2; ++j) {
        const int e = b * 4096 + (j * 256 + t) * 8;
        f32x4 v0 = ((const f32x4*)(W + e))[0];
        f32x4 v1 = ((const f32x4*)(W + e))[1];
        bf16x8 o;
#pragma unroll
        for (int i = 0; i < 4; ++i) {
            o[i]     = (__bf16)rintf(v0[i] / s);
            o[i + 4] = (__bf16)rintf(v1[i] / s);
        }
        *(bf16x8*)(Q + e) = o;
    }
}

// ---------------- dual bf16 MFMA GEMM: 256x128 tile, 8-wave ----------------
// A: f32 source, reg-staged (global f32x4 -> cvt bf16 -> swizzled
//    ds_write_b128) into 2 LDS buffers; conversion fused => no prep pass.
// B: quantized bf16, via global_load_lds DMA, 3 buffers, distance-2.
// One barrier per K-step. Issue order per iter kt:
//   [A-gl(kt+1):8] [16 ds_read] [B-DMA(kt+2):2] lgkm(0) | 32 MFMA |
//   vmcnt(2) (certifies A-gl(kt+1) AND B(kt+1); only B(kt+2) newer) |
//   cvt + 4 ds_write -> bufA[(kt+1)&1] | lgkm(0) | s_barrier
// Race-freedom: reads of bufA[kt&1] retire at this iter's first lgkm(0)
// BEFORE the barrier; the write to bufA[(kt+1)&1] touches the other buffer;
// B overwrite (kt+2)%3 is 2 barriers after its last reader (as round 5).
// Fragment mapping identical to round 5 => bit-identical numerics.
__global__ __launch_bounds__(512, 1)
void gemm_dual(const float* __restrict__ A0, const float* __restrict__ A1,
               const __bf16* __restrict__ W0, const __bf16* __restrict__ W1,
               __bf16* __restrict__ C0, __bf16* __restrict__ C1)
{
    __shared__ bf16x8 ldsA[2][2048];   // 64 KB (256 rows x 64 k, dbuf)
    __shared__ bf16x8 ldsB[3][1024];   // 48 KB (128 rows x 64 k, 3-buf)

    // XCD-aware bijective swizzle (256 blocks, 8 XCDs)
    const int b = blockIdx.x;
    const int swz = (b & 7) * 32 + (b >> 3);
    const int which = swz >> 7;
    const int r = swz & 127;
    const int bm = r >> 3, bn = r & 7;     // bm 0..15 (M/256), bn 0..7 (N/128)

    const float*  A = which ? A1 : A0;
    const __bf16* W = which ? W1 : W0;
    __bf16*       C = which ? C1 : C0;

    const int t = threadIdx.x;
    const int l = t & 63, w = t >> 6;
    const int wm = w >> 1, wn = w & 1;      // wave grid 4M x 2N, per-wave 64x64
    const int l15 = l & 15, l7 = l & 7, lq = l >> 4;

    const float*  gA = A + (size_t)(bm * 256) * KDIM;
    const __bf16* gB = W + (size_t)(bn * 128) * KDIM;

    // A staging: thread t owns chunks c = j*512+t; row = c>>3, g = (c&7)^(row&7)
    int srcA[4];   // f32 element offsets (pre-swizzled)
#pragma unroll
    for (int j = 0; j < 4; ++j) {
        const int c = j * 512 + t;
        const int row = c >> 3, g = (c & 7) ^ (row & 7);
        srcA[j] = row * KDIM + g * 8;
    }
    // B staging source offsets (bf16 elements, pre-swizzled)
    int srcB[2];
#pragma unroll
    for (int j = 0; j < 2; ++j) {
        const int c = j * 512 + t;
        const int row = c >> 3, g = (c & 7) ^ (row & 7);
        srcB[j] = row * KDIM + g * 8;
    }

#define STAGEB(bb, kt)                                                         \
    do {                                                                       \
        _Pragma("unroll")                                                      \
        for (int j = 0; j < 2; ++j)                                            \
            __builtin_amdgcn_global_load_lds(                                  \
                (const __attribute__((address_space(1))) unsigned*)(gB + srcB[j] + (kt) * 64), \
                (__attribute__((address_space(3))) unsigned*)(&ldsB[bb][(j) * 512 + t]), \
                16, 0, 0);                                                     \
    } while (0)

#define ALOAD(kt)                                                              \
    do {                                                                       \
        _Pragma("unroll")                                                      \
        for (int j = 0; j < 4; ++j) {                                          \
            const f32x4* pa = (const f32x4*)(gA + srcA[j] + (kt) * 64);        \
            ar[j][0] = pa[0]; ar[j][1] = pa[1];                                \
        }                                                                      \
    } while (0)

#define AWRITE(bb)                                                             \
    do {                                                                       \
        _Pragma("unroll")                                                      \
        for (int j = 0; j < 4; ++j) {                                          \
            bf16x8 av;                                                         \
            _Pragma("unroll")                                                  \
            for (int i = 0; i < 4; ++i) {                                      \
                av[i]     = (__bf16)ar[j][0][i];                               \
                av[i + 4] = (__bf16)ar[j][1][i];                               \
            }                                                                  \
            ldsA[bb][j * 512 + t] = av;                                        \
        }                                                                      \
    } while (0)

    const f32x4 zero4 = {0.f, 0.f, 0.f, 0.f};
    f32x4 acc[4][4];
#pragma unroll
    for (int mi = 0; mi < 4; ++mi)
#pragma unroll
        for (int ni = 0; ni < 4; ++ni) acc[mi][ni] = zero4;

    f32x4 ar[4][2];

    // prologue: A(0) -> regs -> cvt -> ldsA[0]; stage B(0), B(1)
    ALOAD(0);
    AWRITE(0);                 // compiler auto-waits vmcnt for ar use
    STAGEB(0, 0);
    STAGEB(1, 1);
    asm volatile("s_waitcnt lgkmcnt(0)" ::: "memory");   // A(0) writes done
    asm volatile("s_waitcnt vmcnt(2)" ::: "memory");     // B(0) landed, B(1) in flight
    __builtin_amdgcn_s_barrier();

#pragma unroll
    for (int kt = 0; kt < 16; ++kt) {
        // A global prefetch for kt+1 (issue first: max latency cover)
        if (kt < 15) ALOAD(kt + 1);

        const bf16x8* LA = &ldsA[kt & 1][0];
        const bf16x8* LB = &ldsB[kt % 3][0];
        bf16x8 af[2][4], bfv[2][4];
#pragma unroll
        for (int kk = 0; kk < 2; ++kk) {
            const int kq = kk * 4 + lq;
#pragma unroll
            for (int mi = 0; mi < 4; ++mi)
                af[kk][mi] = LA[(wm * 64 + mi * 16 + l15) * 8 + (kq ^ l7)];
#pragma unroll
            for (int ni = 0; ni < 4; ++ni)
                bfv[kk][ni] = LB[(wn * 64 + ni * 16 + l15) * 8 + (kq ^ l7)];
        }

        if (kt < 14) STAGEB((kt + 2) % 3, kt + 2);

        asm volatile("s_waitcnt lgkmcnt(0)" ::: "memory");   // frags ready, bufA reads retired
        __builtin_amdgcn_sched_barrier(0);

        __builtin_amdgcn_s_setprio(1);
#pragma unroll
        for (int kk = 0; kk < 2; ++kk)
#pragma unroll
            for (int mi = 0; mi < 4; ++mi)
#pragma unroll
                for (int ni = 0; ni < 4; ++ni)
                    acc[mi][ni] = __builtin_amdgcn_mfma_f32_16x16x32_bf16(
                        bfv[kk][ni], af[kk][mi], acc[mi][ni], 0, 0, 0);
        __builtin_amdgcn_s_setprio(0);

        if (kt < 14)       { asm volatile("s_waitcnt vmcnt(2)" ::: "memory"); }
        else if (kt == 14) { asm volatile("s_waitcnt vmcnt(0)" ::: "memory"); }

        if (kt < 15) {
            AWRITE((kt + 1) & 1);                            // cvt + 4 ds_write
            asm volatile("s_waitcnt lgkmcnt(0)" ::: "memory");
            __builtin_amdgcn_s_barrier();
        }
    }

    // C write (swapped-operand layout): batch = lane&15 (+mi*16),
    // feat = (lane>>4)*4 + rr (+ni*16); one 8B bf16x4 store per fragment
    const int batch0 = bm * 256 + wm * 64 + l15;
    const int feat0  = bn * 128 + wn * 64 + (lq << 2);
#pragma unroll
    for (int mi = 0; mi < 4; ++mi)
#pragma unroll
        for (int ni = 0; ni < 4; ++ni) {
            bf16x4 o;
#pragma unroll
            for (int rr = 0; rr < 4; ++rr) o[rr] = (__bf16)acc[mi][ni][rr];
            *(bf16x4*)(C + (size_t)(batch0 + mi * 16) * KDIM + feat0 + ni * 16) = o;
        }
#undef STAGEB
#undef ALOAD
#undef AWRITE
}

// ---------------- fused scale+bias, LN(x), LN(h), tanh — one row per WAVE ----------------
__global__ __launch_bounds__(256)
void ln_tanh_k(const __bf16* __restrict__ X, const __bf16* __restrict__ Hh,
               const float* __restrict__ bi, const float* __restrict__ br,
               const float* __restrict__ scales, float* __restrict__ out)
{
    const int t = threadIdx.x;
    const int lane = t & 63, wid = t >> 6;
    const int row = blockIdx.x * 4 + wid;
    const float si = scales[0];
    const float sr = scales[1];

    const bf16x8* xp = (const bf16x8*)(X  + (size_t)row * 1024 + lane * 16);
    const bf16x8* hp = (const bf16x8*)(Hh + (size_t)row * 1024 + lane * 16);
    bf16x8 xv0 = xp[0], xv1 = xp[1];
    bf16x8 hv0 = hp[0], hv1 = hp[1];

    float xs[16], hs[16];
    float sx = 0.f, sh = 0.f;
#pragma unroll
    for (int q = 0; q < 4; ++q) {
        f32x4 bviq = ((const f32x4*)bi)[lane * 4 + q];
        f32x4 bvrq = ((const f32x4*)br)[lane * 4 + q];
#pragma unroll
        for (int j = 0; j < 4; ++j) {
            const int e = q * 4 + j;
            const float xf = (e < 8) ? (float)xv0[e] : (float)xv1[e - 8];
            const float hf = (e < 8) ? (float)hv0[e] : (float)hv1[e - 8];
            xs[e] = xf * si + bviq[j];
            hs[e] = hf * sr + bvrq[j];
            sx += xs[e]; sh += hs[e];
        }
    }

#pragma unroll
    for (int o = 32; o >= 1; o >>= 1) { sx += __shfl_xor(sx, o); sh += __shfl_xor(sh, o); }
    const float mx = sx * (1.0f / 1024.0f), mh = sh * (1.0f / 1024.0f);

    float vx = 0.f, vh = 0.f;
#pragma unroll
    for (int e = 0; e < 16; ++e) {
        xs[e] -= mx; hs[e] -= mh;
        vx += xs[e] * xs[e]; vh += hs[e] * hs[e];
    }
#pragma unroll
    for (int o = 32; o >= 1; o >>= 1) { vx += __shfl_xor(vx, o); vh += __shfl_xor(vh, o); }
    const float rsx = rsqrtf(vx * (1.0f / 1024.0f) + 1e-5f);
    const float rsh = rsqrtf(vh * (1.0f / 1024.0f) + 1e-5f);

    float* op = out + (size_t)row * 1024 + lane * 16;
#pragma unroll
    for (int q = 0; q < 4; ++q) {
        f32x4 o4;
#pragma unroll
        for (int j = 0; j < 4; ++j) {
            const int e = q * 4 + j;
            o4[j] = tanhf(xs[e] * rsx + hs[e] * rsh);
        }
        ((f32x4*)op)[q] = o4;
    }
}

extern "C" void kernel_launch(void* const* d_in, const int* in_sizes, int n_in,
                              void* d_out, int out_size, void* d_ws, size_t ws_size,
                              hipStream_t stream)
{
    const float* input_ = (const float*)d_in[0];
    const float* hidden = (const float*)d_in[1];
    const float* Wi     = (const float*)d_in[2];
    const float* bi     = (const float*)d_in[3];
    const float* Wr     = (const float*)d_in[4];
    const float* br     = (const float*)d_in[5];
    float* out = (float*)d_out;

    char* ws = (char*)d_ws;
    float* bmax   = (float*)ws;
    float* scales = (float*)(ws + 2048);
    __bf16* Qi = (__bf16*)(ws + 4096);
    __bf16* Qr = (__bf16*)(ws + 4096 + (1u << 21));
    __bf16* Xq = (__bf16*)(ws + 4096 + (2u << 21));
    __bf16* Hq = (__bf16*)(ws + 4096 + (2u << 21) + (1u << 23));

    absmax_k<<<512, 256, 0, stream>>>(Wi, Wr, bmax);
    quant_k<<<512, 256, 0, stream>>>(Wi, Wr, bmax, scales, Qi, Qr);
    gemm_dual<<<256, 512, 0, stream>>>(input_, hidden, Qi, Qr, Xq, Hq);
    ln_tanh_k<<<1024, 256, 0, stream>>>(Xq, Hq, bi, br, scales, out);
}